// Round 1
// baseline (914.012 us; speedup 1.0000x reference)
//
#include <hip/hip_runtime.h>
#include <hip/hip_bf16.h>
#include <cstdio>

#define B     64
#define DIN   1024
#define NPRI  2048
#define DPRI  16
#define NCLS  25
#define DCLS  16
#define EMEPS 1e-6f
#define LNEPS 1e-5f

// ---------------- workspace layout (float offsets) ----------------
#define OFF_POSE 0                                   // [B][NPRI][DPRI]
#define OFF_ZN   (OFF_POSE + B*NPRI*DPRI)            // [B][DIN]
#define OFF_ACTT (OFF_ZN + B*DIN)                    // [NPRI][B]
#define OFF_V    (OFF_ACTT + NPRI*B)                 // [NPRI][NCLS][DCLS][B]
#define OFF_L    (OFF_V + NPRI*NCLS*DCLS*B)          // [NPRI][NCLS][B]
#define OFF_R    (OFF_L + NPRI*NCLS*B)               // [NPRI][NCLS][B]
#define NCHUNK_S 8
#define OFF_PART (OFF_R + NPRI*NCLS*B)               // [NCLS][NCHUNK_S][33][B]
#define OFF_STAT (OFF_PART + NCLS*NCHUNK_S*33*B)     // [NCLS][33][B]
#define OFF_MU   (OFF_STAT + NCLS*33*B)              // [NCLS][DCLS][B]
#define OFF_ISIG (OFF_MU + NCLS*DCLS*B)              // [NCLS][DCLS][B]
#define OFF_LOGA (OFF_ISIG + NCLS*DCLS*B)            // [NCLS][B]
#define OFF_LDET (OFF_LOGA + NCLS*B)                 // [NCLS][B]
#define WS_FLOATS (OFF_LDET + NCLS*B)

// ---------------- LayerNorm over z rows ----------------
__global__ __launch_bounds__(256) void k_ln(const float* __restrict__ z,
                                            const float* __restrict__ g,
                                            const float* __restrict__ bb,
                                            float* __restrict__ zn) {
  int row = blockIdx.x, t = threadIdx.x;
  const float* zr = z + row * DIN;
  float4 v = ((const float4*)zr)[t];
  float s  = v.x + v.y + v.z + v.w;
  float s2 = v.x*v.x + v.y*v.y + v.z*v.z + v.w*v.w;
  for (int off = 32; off; off >>= 1) {
    s  += __shfl_down(s, off);
    s2 += __shfl_down(s2, off);
  }
  __shared__ float ls[8];
  int wv = t >> 6, ln = t & 63;
  if (ln == 0) { ls[wv*2] = s; ls[wv*2+1] = s2; }
  __syncthreads();
  s  = ls[0] + ls[2] + ls[4] + ls[6];
  s2 = ls[1] + ls[3] + ls[5] + ls[7];
  float mean = s * (1.0f / DIN);
  float var  = s2 * (1.0f / DIN) - mean * mean;
  float inv  = 1.0f / sqrtf(var + LNEPS);
  float4 gg = ((const float4*)g)[t];
  float4 bv = ((const float4*)bb)[t];
  float4 o;
  o.x = (v.x - mean) * inv * gg.x + bv.x;
  o.y = (v.y - mean) * inv * gg.y + bv.y;
  o.z = (v.z - mean) * inv * gg.z + bv.z;
  o.w = (v.w - mean) * inv * gg.w + bv.w;
  ((float4*)(zn + row * DIN))[t] = o;
}

// ---------------- GEMM1: pose = z @ w1 + b1  (64x1024 @ 1024x32768) ----------------
// grid (128,2) block 256. Tile: 32 rows x 256 cols per block.
__global__ __launch_bounds__(256) void k_gemm1(const float* __restrict__ z,
                                               const float* __restrict__ w1,
                                               const float* __restrict__ b1,
                                               float* __restrict__ pose) {
  __shared__ __align__(16) float zl[64 * 32];
  int t = threadIdx.x;
  int cg = t & 63, bg = t >> 6;
  int c0 = blockIdx.x * 256 + cg;
  int brow0 = blockIdx.y * 32;
  int bl = t >> 3, kq = t & 7;

  float acc[4][8];
#pragma unroll
  for (int j = 0; j < 4; ++j)
#pragma unroll
    for (int r = 0; r < 8; ++r) acc[j][r] = 0.f;

  for (int kc = 0; kc < 16; ++kc) {
    int k0 = kc * 64;
    __syncthreads();
    const float* zsrc = z + (brow0 + bl) * DIN + k0 + kq * 8;
    float4 a0 = *(const float4*)zsrc;
    float4 a1 = *(const float4*)(zsrc + 4);
    zl[(kq*8+0)*32 + bl] = a0.x; zl[(kq*8+1)*32 + bl] = a0.y;
    zl[(kq*8+2)*32 + bl] = a0.z; zl[(kq*8+3)*32 + bl] = a0.w;
    zl[(kq*8+4)*32 + bl] = a1.x; zl[(kq*8+5)*32 + bl] = a1.y;
    zl[(kq*8+6)*32 + bl] = a1.z; zl[(kq*8+7)*32 + bl] = a1.w;
    __syncthreads();
#pragma unroll 4
    for (int k = 0; k < 64; ++k) {
      const float* wr = w1 + (k0 + k) * 32768 + c0;
      float wa = wr[0], wb = wr[64], wc = wr[128], wd = wr[192];
      const float* zr_ = &zl[k * 32 + bg * 8];
      float4 za = *(const float4*)zr_;
      float4 zb = *(const float4*)(zr_ + 4);
      float zv[8] = {za.x, za.y, za.z, za.w, zb.x, zb.y, zb.z, zb.w};
#pragma unroll
      for (int r = 0; r < 8; ++r) {
        acc[0][r] += wa * zv[r];
        acc[1][r] += wb * zv[r];
        acc[2][r] += wc * zv[r];
        acc[3][r] += wd * zv[r];
      }
    }
  }
#pragma unroll
  for (int j = 0; j < 4; ++j) {
    float bc = b1[c0 + 64 * j];
#pragma unroll
    for (int r = 0; r < 8; ++r)
      pose[(brow0 + bg * 8 + r) * 32768 + c0 + 64 * j] = acc[j][r] + bc;
  }
}

// ---------------- GEMM2: act_t[n][b] = clip(sigmoid(zn @ w2 + b2)) ----------------
// grid (32,2) block 256. Tile: 32 rows x 64 cols.
__global__ __launch_bounds__(256) void k_gemm2(const float* __restrict__ zn,
                                               const float* __restrict__ w2,
                                               const float* __restrict__ b2,
                                               float* __restrict__ actt) {
  __shared__ __align__(16) float zl[64 * 32];
  int t = threadIdx.x;
  int cg = t & 63, bg = t >> 6;
  int c = blockIdx.x * 64 + cg;
  int brow0 = blockIdx.y * 32;
  int bl = t >> 3, kq = t & 7;

  float acc[8];
#pragma unroll
  for (int r = 0; r < 8; ++r) acc[r] = 0.f;

  for (int kc = 0; kc < 16; ++kc) {
    int k0 = kc * 64;
    __syncthreads();
    const float* zsrc = zn + (brow0 + bl) * DIN + k0 + kq * 8;
    float4 a0 = *(const float4*)zsrc;
    float4 a1 = *(const float4*)(zsrc + 4);
    zl[(kq*8+0)*32 + bl] = a0.x; zl[(kq*8+1)*32 + bl] = a0.y;
    zl[(kq*8+2)*32 + bl] = a0.z; zl[(kq*8+3)*32 + bl] = a0.w;
    zl[(kq*8+4)*32 + bl] = a1.x; zl[(kq*8+5)*32 + bl] = a1.y;
    zl[(kq*8+6)*32 + bl] = a1.z; zl[(kq*8+7)*32 + bl] = a1.w;
    __syncthreads();
#pragma unroll 4
    for (int k = 0; k < 64; ++k) {
      float wv = w2[(k0 + k) * 2048 + c];
      const float* zr_ = &zl[k * 32 + bg * 8];
      float4 za = *(const float4*)zr_;
      float4 zb = *(const float4*)(zr_ + 4);
      acc[0] += wv * za.x; acc[1] += wv * za.y; acc[2] += wv * za.z; acc[3] += wv * za.w;
      acc[4] += wv * zb.x; acc[5] += wv * zb.y; acc[6] += wv * zb.z; acc[7] += wv * zb.w;
    }
  }
  float bc = b2[c];
#pragma unroll
  for (int r = 0; r < 8; ++r) {
    float x = acc[r] + bc;
    float s = 1.0f / (1.0f + expf(-x));
    s = fminf(fmaxf(s, 0.0f), 1.0f);
    actt[c * 64 + (brow0 + bg * 8 + r)] = s;
  }
}

// ---------------- votes: V[n][o][d][b] = sum_i pose[b,n,i]*w_caps[n,i,o,d] ----------------
__global__ __launch_bounds__(256) void k_votes(const float* __restrict__ pose,
                                               const float* __restrict__ wcaps,
                                               float* __restrict__ V) {
  __shared__ __align__(16) float wl[6400];
  int n = blockIdx.x, t = threadIdx.x;
  const float* wsrc = wcaps + n * 6400;
  for (int idx = t * 4; idx < 6400; idx += 1024)
    *(float4*)(wl + idx) = *(const float4*)(wsrc + idx);

  int b = t & 63, wv = t >> 6;
  float p[16];
  const float* ps = pose + (b * NPRI + n) * 16;
#pragma unroll
  for (int i = 0; i < 16; i += 4) {
    float4 pv = *(const float4*)(ps + i);
    p[i] = pv.x; p[i+1] = pv.y; p[i+2] = pv.z; p[i+3] = pv.w;
  }
  __syncthreads();
  for (int q = wv; q < 100; q += 4) {
    int o = q >> 2, dq = q & 3;
    float ax = 0.f, ay = 0.f, az = 0.f, aw = 0.f;
#pragma unroll
    for (int i = 0; i < 16; ++i) {
      float4 w4 = *(const float4*)(wl + (i * 25 + o) * 16 + dq * 4);
      ax += p[i] * w4.x; ay += p[i] * w4.y; az += p[i] * w4.z; aw += p[i] * w4.w;
    }
    float* vd = V + ((n * 25 + o) * 16 + dq * 4) * 64 + b;
    vd[0] = ax; vd[64] = ay; vd[128] = az; vd[192] = aw;
  }
}

// ---------------- M-step moment accumulation ----------------
template <bool UNIFORM>
__global__ __launch_bounds__(256) void k_stats(const float* __restrict__ V,
                                               const float* __restrict__ actt,
                                               const float* __restrict__ R,
                                               float* __restrict__ part) {
  int o = blockIdx.y;
  int t = threadIdx.x, b = t & 63, wv = t >> 6;
  float S0 = 0.f, S1[16], S2[16];
#pragma unroll
  for (int d = 0; d < 16; ++d) { S1[d] = 0.f; S2[d] = 0.f; }
  int n0 = blockIdx.x * 256 + wv * 64;
  for (int k = 0; k < 64; ++k) {
    int n = n0 + k;
    float a = actt[n * 64 + b];
    float r = UNIFORM ? a * (1.0f / 25.0f) : R[(n * 25 + o) * 64 + b] * a;
    const float* vp = V + (n * 25 + o) * 1024 + b;
    S0 += r;
#pragma unroll
    for (int d = 0; d < 16; ++d) {
      float v = vp[d * 64];
      S1[d] += r * v;
      S2[d] += r * v * v;
    }
  }
  __shared__ float red[4 * 33 * 64];
  red[(wv * 33 + 0) * 64 + b] = S0;
#pragma unroll
  for (int d = 0; d < 16; ++d) {
    red[(wv * 33 + 1 + d) * 64 + b]  = S1[d];
    red[(wv * 33 + 17 + d) * 64 + b] = S2[d];
  }
  __syncthreads();
  if (wv == 0) {
    for (int s = 0; s < 33; ++s) {
      float tot = red[s * 64 + b] + red[(33 + s) * 64 + b] +
                  red[(66 + s) * 64 + b] + red[(99 + s) * 64 + b];
      part[((o * NCHUNK_S + blockIdx.x) * 33 + s) * 64 + b] = tot;
    }
  }
}

__global__ __launch_bounds__(256) void k_reduce(const float* __restrict__ part,
                                                float* __restrict__ stats) {
  int o = blockIdx.x;
  for (int idx = threadIdx.x; idx < 33 * 64; idx += 256) {
    float s = 0.f;
#pragma unroll
    for (int c = 0; c < NCHUNK_S; ++c)
      s += part[(o * NCHUNK_S + c) * 33 * 64 + idx];
    stats[o * 33 * 64 + idx] = s;
  }
}

// ---------------- finish M-step: mu, 1/sigma2, log a_out, logdet ----------------
__global__ __launch_bounds__(64) void k_finish(const float* __restrict__ stats,
                                               const float* __restrict__ beta_u,
                                               const float* __restrict__ beta_a,
                                               float* __restrict__ mu,
                                               float* __restrict__ isig,
                                               float* __restrict__ loga,
                                               float* __restrict__ ldetw) {
  int o = blockIdx.x, b = threadIdx.x;
  const float* st = stats + o * 33 * 64;
  float s0 = st[b];
  float rs = s0 + EMEPS;
  float inv_rs = 1.0f / rs;
  float ldet = 0.f;
#pragma unroll
  for (int d = 0; d < 16; ++d) {
    float s1 = st[(1 + d) * 64 + b];
    float s2 = st[(17 + d) * 64 + b];
    float m = s1 * inv_rs;
    float var = (s2 - 2.0f * m * s1 + m * m * s0) * inv_rs;
    float sg = fmaxf(var, 0.0f) + EMEPS;
    mu[(o * 16 + d) * 64 + b] = m;
    isig[(o * 16 + d) * 64 + b] = 1.0f / sg;
    ldet += logf(sg);
  }
  float cost = (16.0f * beta_u[o] + 0.5f * ldet) * rs;
  float x = beta_a[o] - cost;
  float a = 1.0f / (1.0f + expf(-x));
  loga[o * 64 + b] = logf(a + EMEPS);
  ldetw[o * 64 + b] = ldet;
}

// ---------------- E-step part 1: L[n][o][b] = log(a)+logp ----------------
__global__ __launch_bounds__(256) void k_logp(const float* __restrict__ V,
                                              const float* __restrict__ mu,
                                              const float* __restrict__ isig,
                                              const float* __restrict__ loga,
                                              const float* __restrict__ ldet,
                                              float* __restrict__ L) {
  int o = blockIdx.y, t = threadIdx.x, b = t & 63, wv = t >> 6;
  float m[16], is[16];
#pragma unroll
  for (int d = 0; d < 16; ++d) {
    m[d]  = mu[(o * 16 + d) * 64 + b];
    is[d] = isig[(o * 16 + d) * 64 + b];
  }
  float base = loga[o * 64 + b] - 0.5f * ldet[o * 64 + b];
  int n0 = blockIdx.x * 64 + wv * 16;
  for (int k = 0; k < 16; ++k) {
    int n = n0 + k;
    const float* vp = V + (n * 25 + o) * 1024 + b;
    float acc = 0.f;
#pragma unroll
    for (int d = 0; d < 16; ++d) {
      float dd = vp[d * 64] - m[d];
      acc += dd * dd * is[d];
    }
    L[(n * 25 + o) * 64 + b] = base - 0.5f * acc;
  }
}

// ---------------- E-step part 2: softmax over o ----------------
template <bool FINAL>
__global__ __launch_bounds__(256) void k_softmax(const float* __restrict__ L,
                                                 float* __restrict__ out) {
  int t = threadIdx.x, b = t & 63, wv = t >> 6;
  int n0 = blockIdx.x * 64 + wv * 16;
  for (int k = 0; k < 16; ++k) {
    int n = n0 + k;
    float v[25];
    float mx = -1e30f;
#pragma unroll
    for (int o = 0; o < 25; ++o) {
      v[o] = L[(n * 25 + o) * 64 + b];
      mx = fmaxf(mx, v[o]);
    }
    float s = 0.f;
#pragma unroll
    for (int o = 0; o < 25; ++o) { v[o] = expf(v[o] - mx); s += v[o]; }
    float inv = 1.0f / s;
#pragma unroll
    for (int o = 0; o < 25; ++o) {
      float r = v[o] * inv;
      if (FINAL) out[(b * NPRI + n) * 25 + o] = r;
      else       out[(n * 25 + o) * 64 + b] = r;
    }
  }
}

// ---------------- epilogue: logits, acts, class_pose ----------------
__global__ __launch_bounds__(64) void k_out(const float* __restrict__ mu,
                                            const float* __restrict__ g2,
                                            const float* __restrict__ bb2,
                                            const float* __restrict__ w3,
                                            const float* __restrict__ b3,
                                            float* __restrict__ out) {
  int o = blockIdx.x, b = threadIdx.x;
  float m[16];
  float s = 0.f;
#pragma unroll
  for (int d = 0; d < 16; ++d) { m[d] = mu[(o * 16 + d) * 64 + b]; s += m[d]; }
  float mean = s * (1.0f / 16.0f);
  float var = 0.f;
#pragma unroll
  for (int d = 0; d < 16; ++d) { float dd = m[d] - mean; var += dd * dd; }
  var *= (1.0f / 16.0f);
  float inv = 1.0f / sqrtf(var + LNEPS);
  float logit = 0.f, nrm = 0.f;
#pragma unroll
  for (int d = 0; d < 16; ++d) {
    float nh = (m[d] - mean) * inv * g2[d] + bb2[d];
    logit += nh * w3[d];
    nrm += m[d] * m[d];
  }
  out[b * 25 + o] = logit + b3[0];
  out[1600 + b * 25 + o] = sqrtf(nrm);
  float* pp = out + 3200 + (b * 25 + o) * 16;
#pragma unroll
  for (int d = 0; d < 16; ++d) pp[d] = m[d];
}

extern "C" void kernel_launch(void* const* d_in, const int* in_sizes, int n_in,
                              void* d_out, int out_size, void* d_ws, size_t ws_size,
                              hipStream_t stream) {
  const float* z      = (const float*)d_in[0];
  const float* w1     = (const float*)d_in[1];
  const float* b1     = (const float*)d_in[2];
  const float* ln1g   = (const float*)d_in[3];
  const float* ln1b   = (const float*)d_in[4];
  const float* w2     = (const float*)d_in[5];
  const float* b2     = (const float*)d_in[6];
  const float* wcaps  = (const float*)d_in[7];
  const float* beta_u = (const float*)d_in[8];
  const float* beta_a = (const float*)d_in[9];
  const float* ln2g   = (const float*)d_in[10];
  const float* ln2b   = (const float*)d_in[11];
  const float* w3     = (const float*)d_in[12];
  const float* b3     = (const float*)d_in[13];

  if (ws_size < (size_t)WS_FLOATS * 4) {
    fprintf(stderr, "kernel_launch: ws too small: %zu < %zu bytes\n",
            ws_size, (size_t)WS_FLOATS * 4);
  }

  float* ws   = (float*)d_ws;
  float* out  = (float*)d_out;
  float* pose = ws + OFF_POSE;
  float* zn   = ws + OFF_ZN;
  float* actt = ws + OFF_ACTT;
  float* V    = ws + OFF_V;
  float* Lw   = ws + OFF_L;
  float* Rws  = ws + OFF_R;
  float* part = ws + OFF_PART;
  float* st   = ws + OFF_STAT;
  float* muw  = ws + OFF_MU;
  float* isw  = ws + OFF_ISIG;
  float* law  = ws + OFF_LOGA;
  float* ldw  = ws + OFF_LDET;

  k_ln<<<64, 256, 0, stream>>>(z, ln1g, ln1b, zn);
  k_gemm1<<<dim3(128, 2), 256, 0, stream>>>(z, w1, b1, pose);
  k_gemm2<<<dim3(32, 2), 256, 0, stream>>>(zn, w2, b2, actt);
  k_votes<<<2048, 256, 0, stream>>>(pose, wcaps, V);

  // iteration 1 (uniform R)
  k_stats<true><<<dim3(NCHUNK_S, 25), 256, 0, stream>>>(V, actt, Rws, part);
  k_reduce<<<25, 256, 0, stream>>>(part, st);
  k_finish<<<25, 64, 0, stream>>>(st, beta_u, beta_a, muw, isw, law, ldw);

  // iterations 2,3
  for (int it = 0; it < 2; ++it) {
    k_logp<<<dim3(32, 25), 256, 0, stream>>>(V, muw, isw, law, ldw, Lw);
    k_softmax<false><<<32, 256, 0, stream>>>(Lw, Rws);
    k_stats<false><<<dim3(NCHUNK_S, 25), 256, 0, stream>>>(V, actt, Rws, part);
    k_reduce<<<25, 256, 0, stream>>>(part, st);
    k_finish<<<25, 64, 0, stream>>>(st, beta_u, beta_a, muw, isw, law, ldw);
  }

  // final E-step -> q, then outputs
  k_logp<<<dim3(32, 25), 256, 0, stream>>>(V, muw, isw, law, ldw, Lw);
  k_softmax<true><<<32, 256, 0, stream>>>(Lw, out + 28800);
  k_out<<<25, 64, 0, stream>>>(muw, ln2g, ln2b, w3, b3, out);
}

// Round 3
// 625.806 us; speedup vs baseline: 1.4605x; 1.4605x over previous
//
#include <hip/hip_runtime.h>
#include <hip/hip_bf16.h>
#include <cstdio>

#define B     64
#define DIN   1024
#define NPRI  2048
#define DPRI  16
#define NCLS  25
#define DCLS  16
#define EMEPS 1e-6f
#define LNEPS 1e-5f

// ---------------- workspace layout (float offsets) ----------------
#define OFF_POSE 0                                   // poseT [NPRI*DPRI][B] f32
#define OFF_ZN   (OFF_POSE + NPRI*DPRI*B)            // [B][DIN]
#define OFF_ACTT (OFF_ZN + B*DIN)                    // [NPRI][B]
#define OFF_V    (OFF_ACTT + NPRI*B)                 // f16 [NPRI][NCLS][B][DCLS] -> /2 floats
#define V_FLOATS (NPRI*NCLS*B*DCLS/2)
#define OFF_L    (OFF_V + V_FLOATS)                  // [NPRI][NCLS][B]
#define OFF_R    (OFF_L + NPRI*NCLS*B)               // [NPRI][NCLS][B]
#define NCHUNK_S 16
#define OFF_PART (OFF_R + NPRI*NCLS*B)               // [NCLS][NCHUNK_S][33][B]
#define OFF_STAT (OFF_PART + NCLS*NCHUNK_S*33*B)     // [NCLS][33][B]
#define OFF_MU   (OFF_STAT + NCLS*33*B)              // [NCLS][DCLS][B]
#define OFF_ISIG (OFF_MU + NCLS*DCLS*B)              // [NCLS][DCLS][B]
#define OFF_LOGA (OFF_ISIG + NCLS*DCLS*B)            // [NCLS][B]
#define OFF_LDET (OFF_LOGA + NCLS*B)                 // [NCLS][B]
#define WS_FLOATS (OFF_LDET + NCLS*B)

// fp16 pack/unpack (RNE convert via _Float16)
__device__ __forceinline__ unsigned pack_f16(float a, float b) {
  union { _Float16 h[2]; unsigned u; } x;
  x.h[0] = (_Float16)a; x.h[1] = (_Float16)b;
  return x.u;
}
__device__ __forceinline__ float f16lo(unsigned u) {
  union { unsigned u; _Float16 h[2]; } x; x.u = u; return (float)x.h[0];
}
__device__ __forceinline__ float f16hi(unsigned u) {
  union { unsigned u; _Float16 h[2]; } x; x.u = u; return (float)x.h[1];
}

// ---------------- LayerNorm over z rows ----------------
__global__ __launch_bounds__(256) void k_ln(const float* __restrict__ z,
                                            const float* __restrict__ g,
                                            const float* __restrict__ bb,
                                            float* __restrict__ zn) {
  int row = blockIdx.x, t = threadIdx.x;
  const float* zr = z + row * DIN;
  float4 v = ((const float4*)zr)[t];
  float s  = v.x + v.y + v.z + v.w;
  float s2 = v.x*v.x + v.y*v.y + v.z*v.z + v.w*v.w;
  for (int off = 32; off; off >>= 1) {
    s  += __shfl_down(s, off);
    s2 += __shfl_down(s2, off);
  }
  __shared__ float ls[8];
  int wv = t >> 6, ln = t & 63;
  if (ln == 0) { ls[wv*2] = s; ls[wv*2+1] = s2; }
  __syncthreads();
  s  = ls[0] + ls[2] + ls[4] + ls[6];
  s2 = ls[1] + ls[3] + ls[5] + ls[7];
  float mean = s * (1.0f / DIN);
  float var  = s2 * (1.0f / DIN) - mean * mean;
  float inv  = 1.0f / sqrtf(var + LNEPS);
  float4 gg = ((const float4*)g)[t];
  float4 bv = ((const float4*)bb)[t];
  float4 o;
  o.x = (v.x - mean) * inv * gg.x + bv.x;
  o.y = (v.y - mean) * inv * gg.y + bv.y;
  o.z = (v.z - mean) * inv * gg.z + bv.z;
  o.w = (v.w - mean) * inv * gg.w + bv.w;
  ((float4*)(zn + row * DIN))[t] = o;
}

// ---------------- GEMM1: poseT[c][r] = (z @ w1 + b1)^T ----------------
__global__ __launch_bounds__(256, 2) void k_gemm1(const float* __restrict__ z,
                                                  const float* __restrict__ w1,
                                                  const float* __restrict__ b1,
                                                  float* __restrict__ poseT) {
  __shared__ __align__(16) float zTl[128 * 68];
  __shared__ __align__(16) float wl[128 * 68];
  int t = threadIdx.x;
  int c0 = blockIdx.x * 64;

  int r0  = (t >> 4) * 4;
  int c0l = (t & 15) * 4;

  int zr_ = t >> 2, za = t & 3;
  int wk = t >> 1, wc = (t & 1) * 32;

  float acc[4][4];
#pragma unroll
  for (int j = 0; j < 4; ++j)
#pragma unroll
    for (int i = 0; i < 4; ++i) acc[j][i] = 0.f;

  for (int kc = 0; kc < 8; ++kc) {
    int k0 = kc * 128;
    __syncthreads();
#pragma unroll
    for (int jj = 0; jj < 4; ++jj) {
      int kb = za * 8 + jj * 32;
      const float* src = z + zr_ * DIN + k0 + kb;
      float4 v0 = *(const float4*)src;
      float4 v1 = *(const float4*)(src + 4);
      zTl[(kb+0)*68 + zr_] = v0.x; zTl[(kb+1)*68 + zr_] = v0.y;
      zTl[(kb+2)*68 + zr_] = v0.z; zTl[(kb+3)*68 + zr_] = v0.w;
      zTl[(kb+4)*68 + zr_] = v1.x; zTl[(kb+5)*68 + zr_] = v1.y;
      zTl[(kb+6)*68 + zr_] = v1.z; zTl[(kb+7)*68 + zr_] = v1.w;
    }
    const float* wsrc = w1 + (size_t)(k0 + wk) * 32768 + c0 + wc;
#pragma unroll
    for (int j = 0; j < 8; ++j)
      *(float4*)&wl[wk * 68 + wc + j * 4] = *(const float4*)(wsrc + j * 4);
    __syncthreads();

#pragma unroll 4
    for (int k = 0; k < 128; ++k) {
      float4 zr4 = *(const float4*)&zTl[k * 68 + r0];
      float4 wr4 = *(const float4*)&wl[k * 68 + c0l];
      float zz[4] = {zr4.x, zr4.y, zr4.z, zr4.w};
      float ww[4] = {wr4.x, wr4.y, wr4.z, wr4.w};
#pragma unroll
      for (int j = 0; j < 4; ++j)
#pragma unroll
        for (int i = 0; i < 4; ++i) acc[j][i] += ww[j] * zz[i];
    }
  }
#pragma unroll
  for (int j = 0; j < 4; ++j) {
    int c = c0 + c0l + j;
    float bc = b1[c];
    float4 o = {acc[j][0] + bc, acc[j][1] + bc, acc[j][2] + bc, acc[j][3] + bc};
    *(float4*)&poseT[c * 64 + r0] = o;
  }
}

// ---------------- GEMM2: act_t[n][b] = clip(sigmoid(zn @ w2 + b2)) ----------------
__global__ __launch_bounds__(256) void k_gemm2(const float* __restrict__ zn,
                                               const float* __restrict__ w2,
                                               const float* __restrict__ b2,
                                               float* __restrict__ actt) {
  __shared__ __align__(16) float zl[64 * 32];
  int t = threadIdx.x;
  int cg = t & 63, bg = t >> 6;
  int c = blockIdx.x * 64 + cg;
  int brow0 = blockIdx.y * 32;
  int bl = t >> 3, kq = t & 7;

  float acc[8];
#pragma unroll
  for (int r = 0; r < 8; ++r) acc[r] = 0.f;

  for (int kc = 0; kc < 16; ++kc) {
    int k0 = kc * 64;
    __syncthreads();
    const float* zsrc = zn + (brow0 + bl) * DIN + k0 + kq * 8;
    float4 a0 = *(const float4*)zsrc;
    float4 a1 = *(const float4*)(zsrc + 4);
    zl[(kq*8+0)*32 + bl] = a0.x; zl[(kq*8+1)*32 + bl] = a0.y;
    zl[(kq*8+2)*32 + bl] = a0.z; zl[(kq*8+3)*32 + bl] = a0.w;
    zl[(kq*8+4)*32 + bl] = a1.x; zl[(kq*8+5)*32 + bl] = a1.y;
    zl[(kq*8+6)*32 + bl] = a1.z; zl[(kq*8+7)*32 + bl] = a1.w;
    __syncthreads();
#pragma unroll 4
    for (int k = 0; k < 64; ++k) {
      float wv = w2[(k0 + k) * 2048 + c];
      const float* zr_ = &zl[k * 32 + bg * 8];
      float4 za = *(const float4*)zr_;
      float4 zb = *(const float4*)(zr_ + 4);
      acc[0] += wv * za.x; acc[1] += wv * za.y; acc[2] += wv * za.z; acc[3] += wv * za.w;
      acc[4] += wv * zb.x; acc[5] += wv * zb.y; acc[6] += wv * zb.z; acc[7] += wv * zb.w;
    }
  }
  float bc = b2[c];
#pragma unroll
  for (int r = 0; r < 8; ++r) {
    float x = acc[r] + bc;
    float s = 1.0f / (1.0f + expf(-x));
    s = fminf(fmaxf(s, 0.0f), 1.0f);
    actt[c * 64 + (brow0 + bg * 8 + r)] = s;
  }
}

// ---------------- votes: V[n][o][b][d] (f16) ----------------
__global__ __launch_bounds__(256) void k_votes(const float* __restrict__ poseT,
                                               const float* __restrict__ wcaps,
                                               unsigned* __restrict__ V) {
  __shared__ __align__(16) float wl[6400];    // [i][o][d]
  __shared__ __align__(16) float pl[64 * 16]; // [b][i]
  int n = blockIdx.x, t = threadIdx.x;
  const float* wsrc = wcaps + (size_t)n * 6400;
  for (int idx = t * 4; idx < 6400; idx += 1024)
    *(float4*)(wl + idx) = *(const float4*)(wsrc + idx);
  {
    float4 v = *(const float4*)(poseT + n * 1024 + t * 4);
    int i = (t * 4) >> 6, b = (t * 4) & 63;
    pl[(b+0)*16 + i] = v.x; pl[(b+1)*16 + i] = v.y;
    pl[(b+2)*16 + i] = v.z; pl[(b+3)*16 + i] = v.w;
  }
  __syncthreads();
  if (t >= 200) return;
  int o = t / 8, d0 = (t % 8) * 2;
  float w0[16], w1_[16];
#pragma unroll
  for (int i = 0; i < 16; ++i) {
    w0[i]  = wl[(i * 25 + o) * 16 + d0];
    w1_[i] = wl[(i * 25 + o) * 16 + d0 + 1];
  }
  unsigned* vd = V + (((size_t)n * 25 + o) * 64 * 16 + d0) / 2;
  for (int b = 0; b < 64; ++b) {
    const float* pb = &pl[b * 16];
    float a0 = 0.f, a1 = 0.f;
#pragma unroll
    for (int i = 0; i < 16; ++i) {
      float p = pb[i];
      a0 += p * w0[i];
      a1 += p * w1_[i];
    }
    vd[b * 8] = pack_f16(a0, a1);
  }
}

// ---------------- M-step moment accumulation (V f16) ----------------
template <bool UNIFORM>
__global__ __launch_bounds__(256) void k_stats(const unsigned* __restrict__ V,
                                               const float* __restrict__ actt,
                                               const float* __restrict__ R,
                                               float* __restrict__ part) {
  int o = blockIdx.y;
  int t = threadIdx.x, b = t & 63, wv = t >> 6;
  float S0 = 0.f, S1[16], S2[16];
#pragma unroll
  for (int d = 0; d < 16; ++d) { S1[d] = 0.f; S2[d] = 0.f; }
  int n0 = blockIdx.x * 128 + wv * 32;
  for (int k = 0; k < 32; ++k) {
    int n = n0 + k;
    float a = actt[n * 64 + b];
    float r = UNIFORM ? a * (1.0f / 25.0f) : R[(n * 25 + o) * 64 + b] * a;
    const uint4* vp = (const uint4*)(V + (((size_t)n * 25 + o) * 64 + b) * 8);
    uint4 u0 = vp[0], u1 = vp[1];
    unsigned uu[8] = {u0.x, u0.y, u0.z, u0.w, u1.x, u1.y, u1.z, u1.w};
    S0 += r;
#pragma unroll
    for (int q = 0; q < 8; ++q) {
      float v0 = f16lo(uu[q]), v1 = f16hi(uu[q]);
      float t0 = r * v0, t1 = r * v1;
      S1[2*q]   += t0;          S1[2*q+1] += t1;
      S2[2*q]   += t0 * v0;     S2[2*q+1] += t1 * v1;
    }
  }
  __shared__ float red[4 * 33 * 64];
  red[(wv * 33 + 0) * 64 + b] = S0;
#pragma unroll
  for (int d = 0; d < 16; ++d) {
    red[(wv * 33 + 1 + d) * 64 + b]  = S1[d];
    red[(wv * 33 + 17 + d) * 64 + b] = S2[d];
  }
  __syncthreads();
  if (wv == 0) {
    for (int s = 0; s < 33; ++s) {
      float tot = red[s * 64 + b] + red[(33 + s) * 64 + b] +
                  red[(66 + s) * 64 + b] + red[(99 + s) * 64 + b];
      part[((o * NCHUNK_S + blockIdx.x) * 33 + s) * 64 + b] = tot;
    }
  }
}

__global__ __launch_bounds__(256) void k_reduce(const float* __restrict__ part,
                                                float* __restrict__ stats) {
  int o = blockIdx.x;
  for (int idx = threadIdx.x; idx < 33 * 64; idx += 256) {
    float s = 0.f;
#pragma unroll
    for (int c = 0; c < NCHUNK_S; ++c)
      s += part[(o * NCHUNK_S + c) * 33 * 64 + idx];
    stats[o * 33 * 64 + idx] = s;
  }
}

// ---------------- finish M-step ----------------
__global__ __launch_bounds__(64) void k_finish(const float* __restrict__ stats,
                                               const float* __restrict__ beta_u,
                                               const float* __restrict__ beta_a,
                                               float* __restrict__ mu,
                                               float* __restrict__ isig,
                                               float* __restrict__ loga,
                                               float* __restrict__ ldetw) {
  int o = blockIdx.x, b = threadIdx.x;
  const float* st = stats + o * 33 * 64;
  float s0 = st[b];
  float rs = s0 + EMEPS;
  float inv_rs = 1.0f / rs;
  float ldet = 0.f;
#pragma unroll
  for (int d = 0; d < 16; ++d) {
    float s1 = st[(1 + d) * 64 + b];
    float s2 = st[(17 + d) * 64 + b];
    float m = s1 * inv_rs;
    float var = (s2 - 2.0f * m * s1 + m * m * s0) * inv_rs;
    float sg = fmaxf(var, 0.0f) + EMEPS;
    mu[(o * 16 + d) * 64 + b] = m;
    isig[(o * 16 + d) * 64 + b] = 1.0f / sg;
    ldet += logf(sg);
  }
  float cost = (16.0f * beta_u[o] + 0.5f * ldet) * rs;
  float x = beta_a[o] - cost;
  float a = 1.0f / (1.0f + expf(-x));
  loga[o * 64 + b] = logf(a + EMEPS);
  ldetw[o * 64 + b] = ldet;
}

// ---------------- E-step part 1 (V f16) ----------------
__global__ __launch_bounds__(256) void k_logp(const unsigned* __restrict__ V,
                                              const float* __restrict__ mu,
                                              const float* __restrict__ isig,
                                              const float* __restrict__ loga,
                                              const float* __restrict__ ldet,
                                              float* __restrict__ L) {
  int o = blockIdx.y, t = threadIdx.x, b = t & 63, wv = t >> 6;
  float m[16], is[16];
#pragma unroll
  for (int d = 0; d < 16; ++d) {
    m[d]  = mu[(o * 16 + d) * 64 + b];
    is[d] = isig[(o * 16 + d) * 64 + b];
  }
  float base = loga[o * 64 + b] - 0.5f * ldet[o * 64 + b];
  int n0 = blockIdx.x * 64 + wv * 16;
  for (int k = 0; k < 16; ++k) {
    int n = n0 + k;
    const uint4* vp = (const uint4*)(V + (((size_t)n * 25 + o) * 64 + b) * 8);
    uint4 u0 = vp[0], u1 = vp[1];
    unsigned uu[8] = {u0.x, u0.y, u0.z, u0.w, u1.x, u1.y, u1.z, u1.w};
    float acc = 0.f;
#pragma unroll
    for (int q = 0; q < 8; ++q) {
      float d0 = f16lo(uu[q]) - m[2*q];
      float d1 = f16hi(uu[q]) - m[2*q+1];
      acc += d0 * d0 * is[2*q] + d1 * d1 * is[2*q+1];
    }
    L[(n * 25 + o) * 64 + b] = base - 0.5f * acc;
  }
}

// ---------------- E-step part 2: softmax over o ----------------
template <bool FINAL>
__global__ __launch_bounds__(256) void k_softmax(const float* __restrict__ L,
                                                 float* __restrict__ out) {
  int t = threadIdx.x, b = t & 63, wv = t >> 6;
  int n0 = blockIdx.x * 64 + wv * 16;
  for (int k = 0; k < 16; ++k) {
    int n = n0 + k;
    float v[25];
    float mx = -1e30f;
#pragma unroll
    for (int o = 0; o < 25; ++o) {
      v[o] = L[(n * 25 + o) * 64 + b];
      mx = fmaxf(mx, v[o]);
    }
    float s = 0.f;
#pragma unroll
    for (int o = 0; o < 25; ++o) { v[o] = expf(v[o] - mx); s += v[o]; }
    float inv = 1.0f / s;
#pragma unroll
    for (int o = 0; o < 25; ++o) {
      float r = v[o] * inv;
      if (FINAL) out[((size_t)b * NPRI + n) * 25 + o] = r;
      else       out[(n * 25 + o) * 64 + b] = r;
    }
  }
}

// ---------------- epilogue ----------------
__global__ __launch_bounds__(64) void k_out(const float* __restrict__ mu,
                                            const float* __restrict__ g2,
                                            const float* __restrict__ bb2,
                                            const float* __restrict__ w3,
                                            const float* __restrict__ b3,
                                            float* __restrict__ out) {
  int o = blockIdx.x, b = threadIdx.x;
  float m[16];
  float s = 0.f;
#pragma unroll
  for (int d = 0; d < 16; ++d) { m[d] = mu[(o * 16 + d) * 64 + b]; s += m[d]; }
  float mean = s * (1.0f / 16.0f);
  float var = 0.f;
#pragma unroll
  for (int d = 0; d < 16; ++d) { float dd = m[d] - mean; var += dd * dd; }
  var *= (1.0f / 16.0f);
  float inv = 1.0f / sqrtf(var + LNEPS);
  float logit = 0.f, nrm = 0.f;
#pragma unroll
  for (int d = 0; d < 16; ++d) {
    float nh = (m[d] - mean) * inv * g2[d] + bb2[d];
    logit += nh * w3[d];
    nrm += m[d] * m[d];
  }
  out[b * 25 + o] = logit + b3[0];
  out[1600 + b * 25 + o] = sqrtf(nrm);
  float* pp = out + 3200 + (b * 25 + o) * 16;
#pragma unroll
  for (int d = 0; d < 16; ++d) pp[d] = m[d];
}

extern "C" void kernel_launch(void* const* d_in, const int* in_sizes, int n_in,
                              void* d_out, int out_size, void* d_ws, size_t ws_size,
                              hipStream_t stream) {
  const float* z      = (const float*)d_in[0];
  const float* w1     = (const float*)d_in[1];
  const float* b1     = (const float*)d_in[2];
  const float* ln1g   = (const float*)d_in[3];
  const float* ln1b   = (const float*)d_in[4];
  const float* w2     = (const float*)d_in[5];
  const float* b2     = (const float*)d_in[6];
  const float* wcaps  = (const float*)d_in[7];
  const float* beta_u = (const float*)d_in[8];
  const float* beta_a = (const float*)d_in[9];
  const float* ln2g   = (const float*)d_in[10];
  const float* ln2b   = (const float*)d_in[11];
  const float* w3     = (const float*)d_in[12];
  const float* b3     = (const float*)d_in[13];

  if (ws_size < (size_t)WS_FLOATS * 4) {
    fprintf(stderr, "kernel_launch: ws too small: %zu < %zu bytes\n",
            ws_size, (size_t)WS_FLOATS * 4);
  }

  float* ws    = (float*)d_ws;
  float* out   = (float*)d_out;
  float* poseT = ws + OFF_POSE;
  float* zn    = ws + OFF_ZN;
  float* actt  = ws + OFF_ACTT;
  unsigned* V  = (unsigned*)(ws + OFF_V);
  float* Lw    = ws + OFF_L;
  float* Rws   = ws + OFF_R;
  float* part  = ws + OFF_PART;
  float* st    = ws + OFF_STAT;
  float* muw   = ws + OFF_MU;
  float* isw   = ws + OFF_ISIG;
  float* law   = ws + OFF_LOGA;
  float* ldw   = ws + OFF_LDET;

  k_ln<<<64, 256, 0, stream>>>(z, ln1g, ln1b, zn);
  k_gemm1<<<512, 256, 0, stream>>>(z, w1, b1, poseT);
  k_gemm2<<<dim3(32, 2), 256, 0, stream>>>(zn, w2, b2, actt);
  k_votes<<<2048, 256, 0, stream>>>(poseT, wcaps, V);

  // iteration 1 (uniform R)
  k_stats<true><<<dim3(NCHUNK_S, 25), 256, 0, stream>>>(V, actt, Rws, part);
  k_reduce<<<25, 256, 0, stream>>>(part, st);
  k_finish<<<25, 64, 0, stream>>>(st, beta_u, beta_a, muw, isw, law, ldw);

  // iterations 2,3
  for (int it = 0; it < 2; ++it) {
    k_logp<<<dim3(32, 25), 256, 0, stream>>>(V, muw, isw, law, ldw, Lw);
    k_softmax<false><<<32, 256, 0, stream>>>(Lw, Rws);
    k_stats<false><<<dim3(NCHUNK_S, 25), 256, 0, stream>>>(V, actt, Rws, part);
    k_reduce<<<25, 256, 0, stream>>>(part, st);
    k_finish<<<25, 64, 0, stream>>>(st, beta_u, beta_a, muw, isw, law, ldw);
  }

  // final E-step -> q, then outputs
  k_logp<<<dim3(32, 25), 256, 0, stream>>>(V, muw, isw, law, ldw, Lw);
  k_softmax<true><<<32, 256, 0, stream>>>(Lw, out + 28800);
  k_out<<<25, 64, 0, stream>>>(muw, ln2g, ln2b, w3, b3, out);
}

// Round 4
// 392.349 us; speedup vs baseline: 2.3296x; 1.5950x over previous
//
#include <hip/hip_runtime.h>
#include <hip/hip_bf16.h>
#include <cstdio>

#define B     64
#define DIN   1024
#define NPRI  2048
#define DPRI  16
#define NCLS  25
#define DCLS  16
#define EMEPS 1e-6f
#define LNEPS 1e-5f
#define KS2   8
#define NCHUNK_S 16

// ---------------- workspace layout (float offsets) ----------------
#define OFF_POSE 0                                   // poseT [NPRI*DPRI][B] f32
#define OFF_ZN   (OFF_POSE + NPRI*DPRI*B)            // [B][DIN]
#define OFF_ACTT (OFF_ZN + B*DIN)                    // [NPRI][B]
#define OFF_G2P  (OFF_ACTT + NPRI*B)                 // gemm2 partial [KS2][NPRI][B]
#define OFF_V    (OFF_G2P + KS2*NPRI*B)              // f16 [NPRI][NCLS][B][DCLS]
#define V_FLOATS (NPRI*NCLS*B*DCLS/2)
#define OFF_R    (OFF_V + V_FLOATS)                  // f16 [NPRI][NCLS][B]
#define R_FLOATS (NPRI*NCLS*B/2)
#define OFF_PART (OFF_R + R_FLOATS)                  // [NCLS][NCHUNK_S][33][B]
#define OFF_STAT (OFF_PART + NCLS*NCHUNK_S*33*B)     // [NCLS][33][B]
#define OFF_MU   (OFF_STAT + NCLS*33*B)              // [NCLS][DCLS][B]
#define OFF_MI4  (OFF_MU + NCLS*DCLS*B)              // float4 [NCLS][8][B]
#define OFF_BASE (OFF_MI4 + NCLS*8*B*4)              // [NCLS][B]
#define WS_FLOATS (OFF_BASE + NCLS*B)

// fp16 pack/unpack
__device__ __forceinline__ unsigned pack_f16(float a, float b) {
  union { _Float16 h[2]; unsigned u; } x;
  x.h[0] = (_Float16)a; x.h[1] = (_Float16)b;
  return x.u;
}
__device__ __forceinline__ float f16lo(unsigned u) {
  union { unsigned u; _Float16 h[2]; } x; x.u = u; return (float)x.h[0];
}
__device__ __forceinline__ float f16hi(unsigned u) {
  union { unsigned u; _Float16 h[2]; } x; x.u = u; return (float)x.h[1];
}
__device__ __forceinline__ unsigned short f16bits(float a) {
  union { _Float16 h; unsigned short u; } x; x.h = (_Float16)a; return x.u;
}
__device__ __forceinline__ float f16val(unsigned short u) {
  union { unsigned short u; _Float16 h; } x; x.u = u; return (float)x.h;
}

// ---------------- LayerNorm over z rows ----------------
__global__ __launch_bounds__(256) void k_ln(const float* __restrict__ z,
                                            const float* __restrict__ g,
                                            const float* __restrict__ bb,
                                            float* __restrict__ zn) {
  int row = blockIdx.x, t = threadIdx.x;
  const float* zr = z + row * DIN;
  float4 v = ((const float4*)zr)[t];
  float s  = v.x + v.y + v.z + v.w;
  float s2 = v.x*v.x + v.y*v.y + v.z*v.z + v.w*v.w;
  for (int off = 32; off; off >>= 1) {
    s  += __shfl_down(s, off);
    s2 += __shfl_down(s2, off);
  }
  __shared__ float ls[8];
  int wv = t >> 6, ln = t & 63;
  if (ln == 0) { ls[wv*2] = s; ls[wv*2+1] = s2; }
  __syncthreads();
  s  = ls[0] + ls[2] + ls[4] + ls[6];
  s2 = ls[1] + ls[3] + ls[5] + ls[7];
  float mean = s * (1.0f / DIN);
  float var  = s2 * (1.0f / DIN) - mean * mean;
  float inv  = 1.0f / sqrtf(var + LNEPS);
  float4 gg = ((const float4*)g)[t];
  float4 bv = ((const float4*)bb)[t];
  float4 o;
  o.x = (v.x - mean) * inv * gg.x + bv.x;
  o.y = (v.y - mean) * inv * gg.y + bv.y;
  o.z = (v.z - mean) * inv * gg.z + bv.z;
  o.w = (v.w - mean) * inv * gg.w + bv.w;
  ((float4*)(zn + row * DIN))[t] = o;
}

// ---------------- GEMM1: poseT[c][r] = (z @ w1 + b1)^T ----------------
__global__ __launch_bounds__(256, 2) void k_gemm1(const float* __restrict__ z,
                                                  const float* __restrict__ w1,
                                                  const float* __restrict__ b1,
                                                  float* __restrict__ poseT) {
  __shared__ __align__(16) float zTl[128 * 68];
  __shared__ __align__(16) float wl[128 * 68];
  int t = threadIdx.x;
  int c0 = blockIdx.x * 64;

  int r0  = (t >> 4) * 4;
  int c0l = (t & 15) * 4;

  int zr_ = t >> 2, za = t & 3;
  int wk = t >> 1, wc = (t & 1) * 32;

  float acc[4][4];
#pragma unroll
  for (int j = 0; j < 4; ++j)
#pragma unroll
    for (int i = 0; i < 4; ++i) acc[j][i] = 0.f;

  for (int kc = 0; kc < 8; ++kc) {
    int k0 = kc * 128;
    __syncthreads();
#pragma unroll
    for (int jj = 0; jj < 4; ++jj) {
      int kb = za * 8 + jj * 32;
      const float* src = z + zr_ * DIN + k0 + kb;
      float4 v0 = *(const float4*)src;
      float4 v1 = *(const float4*)(src + 4);
      zTl[(kb+0)*68 + zr_] = v0.x; zTl[(kb+1)*68 + zr_] = v0.y;
      zTl[(kb+2)*68 + zr_] = v0.z; zTl[(kb+3)*68 + zr_] = v0.w;
      zTl[(kb+4)*68 + zr_] = v1.x; zTl[(kb+5)*68 + zr_] = v1.y;
      zTl[(kb+6)*68 + zr_] = v1.z; zTl[(kb+7)*68 + zr_] = v1.w;
    }
    const float* wsrc = w1 + (size_t)(k0 + wk) * 32768 + c0 + wc;
#pragma unroll
    for (int j = 0; j < 8; ++j)
      *(float4*)&wl[wk * 68 + wc + j * 4] = *(const float4*)(wsrc + j * 4);
    __syncthreads();

#pragma unroll 4
    for (int k = 0; k < 128; ++k) {
      float4 zr4 = *(const float4*)&zTl[k * 68 + r0];
      float4 wr4 = *(const float4*)&wl[k * 68 + c0l];
      float zz[4] = {zr4.x, zr4.y, zr4.z, zr4.w};
      float ww[4] = {wr4.x, wr4.y, wr4.z, wr4.w};
#pragma unroll
      for (int j = 0; j < 4; ++j)
#pragma unroll
        for (int i = 0; i < 4; ++i) acc[j][i] += ww[j] * zz[i];
    }
  }
#pragma unroll
  for (int j = 0; j < 4; ++j) {
    int c = c0 + c0l + j;
    float bc = b1[c];
    float4 o = {acc[j][0] + bc, acc[j][1] + bc, acc[j][2] + bc, acc[j][3] + bc};
    *(float4*)&poseT[c * 64 + r0] = o;
  }
}

// ---------------- GEMM2 k-split partial: part[kz][c][b] ----------------
__global__ __launch_bounds__(256, 2) void k_gemm2p(const float* __restrict__ zn,
                                                   const float* __restrict__ w2,
                                                   float* __restrict__ part) {
  __shared__ __align__(16) float znT[128 * 68];
  __shared__ __align__(16) float wl[128 * 68];
  int t = threadIdx.x;
  int c0 = blockIdx.x * 64;
  int k0 = blockIdx.y * 128;
  int zr_ = t >> 2, za = t & 3;
  int wk = t >> 1, wc = (t & 1) * 32;

#pragma unroll
  for (int jj = 0; jj < 4; ++jj) {
    int kb = za * 8 + jj * 32;
    const float* src = zn + zr_ * DIN + k0 + kb;
    float4 v0 = *(const float4*)src;
    float4 v1 = *(const float4*)(src + 4);
    znT[(kb+0)*68 + zr_] = v0.x; znT[(kb+1)*68 + zr_] = v0.y;
    znT[(kb+2)*68 + zr_] = v0.z; znT[(kb+3)*68 + zr_] = v0.w;
    znT[(kb+4)*68 + zr_] = v1.x; znT[(kb+5)*68 + zr_] = v1.y;
    znT[(kb+6)*68 + zr_] = v1.z; znT[(kb+7)*68 + zr_] = v1.w;
  }
  const float* wsrc = w2 + (size_t)(k0 + wk) * NPRI + c0 + wc;
#pragma unroll
  for (int j = 0; j < 8; ++j)
    *(float4*)&wl[wk * 68 + wc + j * 4] = *(const float4*)(wsrc + j * 4);
  __syncthreads();

  int r0 = (t >> 4) * 4, c0l = (t & 15) * 4;
  float acc[4][4];
#pragma unroll
  for (int j = 0; j < 4; ++j)
#pragma unroll
    for (int i = 0; i < 4; ++i) acc[j][i] = 0.f;

#pragma unroll 4
  for (int k = 0; k < 128; ++k) {
    float4 z4 = *(const float4*)&znT[k * 68 + r0];
    float4 w4 = *(const float4*)&wl[k * 68 + c0l];
    float zz[4] = {z4.x, z4.y, z4.z, z4.w};
    float ww[4] = {w4.x, w4.y, w4.z, w4.w};
#pragma unroll
    for (int j = 0; j < 4; ++j)
#pragma unroll
      for (int i = 0; i < 4; ++i) acc[j][i] += ww[j] * zz[i];
  }
  float* pdst = part + ((size_t)blockIdx.y * NPRI + c0 + c0l) * 64 + r0;
#pragma unroll
  for (int j = 0; j < 4; ++j) {
    float4 o = {acc[j][0], acc[j][1], acc[j][2], acc[j][3]};
    *(float4*)&pdst[j * 64] = o;
  }
}

// ---------------- GEMM2 reduce + sigmoid + clip -> actt[n][b] ----------------
__global__ __launch_bounds__(256) void k_gemm2r(const float* __restrict__ part,
                                                const float* __restrict__ b2,
                                                float* __restrict__ actt) {
  int idx = blockIdx.x * 256 + threadIdx.x;  // float4 index over [c][b]
  float4 s = {0.f, 0.f, 0.f, 0.f};
#pragma unroll
  for (int kz = 0; kz < KS2; ++kz) {
    float4 v = *(const float4*)&part[(size_t)kz * NPRI * 64 + idx * 4];
    s.x += v.x; s.y += v.y; s.z += v.z; s.w += v.w;
  }
  int c = (idx * 4) >> 6;
  float bc = b2[c];
  float4 o;
  o.x = fminf(fmaxf(1.0f / (1.0f + expf(-(s.x + bc))), 0.0f), 1.0f);
  o.y = fminf(fmaxf(1.0f / (1.0f + expf(-(s.y + bc))), 0.0f), 1.0f);
  o.z = fminf(fmaxf(1.0f / (1.0f + expf(-(s.z + bc))), 0.0f), 1.0f);
  o.w = fminf(fmaxf(1.0f / (1.0f + expf(-(s.w + bc))), 0.0f), 1.0f);
  *(float4*)&actt[idx * 4] = o;
}

// ---------------- votes: V[n][o][b][d] (f16) ----------------
__global__ __launch_bounds__(256) void k_votes(const float* __restrict__ poseT,
                                               const float* __restrict__ wcaps,
                                               unsigned* __restrict__ V) {
  __shared__ __align__(16) float wl[6400];    // [i][o][d]
  __shared__ __align__(16) float pl[64 * 16]; // [b][i]
  int n = blockIdx.x, t = threadIdx.x;
  const float* wsrc = wcaps + (size_t)n * 6400;
  for (int idx = t * 4; idx < 6400; idx += 1024)
    *(float4*)(wl + idx) = *(const float4*)(wsrc + idx);
  {
    float4 v = *(const float4*)(poseT + n * 1024 + t * 4);
    int i = (t * 4) >> 6, b = (t * 4) & 63;
    pl[(b+0)*16 + i] = v.x; pl[(b+1)*16 + i] = v.y;
    pl[(b+2)*16 + i] = v.z; pl[(b+3)*16 + i] = v.w;
  }
  __syncthreads();
  if (t >= 200) return;
  int o = t / 8, d0 = (t % 8) * 2;
  float w0[16], w1_[16];
#pragma unroll
  for (int i = 0; i < 16; ++i) {
    w0[i]  = wl[(i * 25 + o) * 16 + d0];
    w1_[i] = wl[(i * 25 + o) * 16 + d0 + 1];
  }
  unsigned* vd = V + (((size_t)n * 25 + o) * 64 * 16 + d0) / 2;
  for (int b = 0; b < 64; ++b) {
    const float* pb = &pl[b * 16];
    float a0 = 0.f, a1 = 0.f;
#pragma unroll
    for (int i = 0; i < 16; ++i) {
      float p = pb[i];
      a0 += p * w0[i];
      a1 += p * w1_[i];
    }
    vd[b * 8] = pack_f16(a0, a1);
  }
}

// ---------------- M-step moment accumulation (V f16, R f16) ----------------
template <bool UNIFORM>
__global__ __launch_bounds__(256) void k_stats(const unsigned* __restrict__ V,
                                               const float* __restrict__ actt,
                                               const unsigned short* __restrict__ Rh,
                                               float* __restrict__ part) {
  int o = blockIdx.y;
  int t = threadIdx.x, b = t & 63, wv = t >> 6;
  float S0 = 0.f, S1[16], S2[16];
#pragma unroll
  for (int d = 0; d < 16; ++d) { S1[d] = 0.f; S2[d] = 0.f; }
  int n0 = blockIdx.x * 128 + wv * 32;
  for (int k = 0; k < 32; ++k) {
    int n = n0 + k;
    float a = actt[n * 64 + b];
    float r = UNIFORM ? a * (1.0f / 25.0f)
                      : f16val(Rh[((size_t)n * 25 + o) * 64 + b]) * a;
    const uint4* vp = (const uint4*)(V + (((size_t)n * 25 + o) * 64 + b) * 8);
    uint4 u0 = vp[0], u1 = vp[1];
    unsigned uu[8] = {u0.x, u0.y, u0.z, u0.w, u1.x, u1.y, u1.z, u1.w};
    S0 += r;
#pragma unroll
    for (int q = 0; q < 8; ++q) {
      float v0 = f16lo(uu[q]), v1 = f16hi(uu[q]);
      float t0 = r * v0, t1 = r * v1;
      S1[2*q]   += t0;          S1[2*q+1] += t1;
      S2[2*q]   += t0 * v0;     S2[2*q+1] += t1 * v1;
    }
  }
  __shared__ float red[4 * 33 * 64];
  red[(wv * 33 + 0) * 64 + b] = S0;
#pragma unroll
  for (int d = 0; d < 16; ++d) {
    red[(wv * 33 + 1 + d) * 64 + b]  = S1[d];
    red[(wv * 33 + 17 + d) * 64 + b] = S2[d];
  }
  __syncthreads();
  if (wv == 0) {
    for (int s = 0; s < 33; ++s) {
      float tot = red[s * 64 + b] + red[(33 + s) * 64 + b] +
                  red[(66 + s) * 64 + b] + red[(99 + s) * 64 + b];
      part[((o * NCHUNK_S + blockIdx.x) * 33 + s) * 64 + b] = tot;
    }
  }
}

__global__ __launch_bounds__(256) void k_reduce(const float* __restrict__ part,
                                                float* __restrict__ stats) {
  int o = blockIdx.x;
  for (int idx = threadIdx.x; idx < 33 * 64; idx += 256) {
    float s = 0.f;
#pragma unroll
    for (int c = 0; c < NCHUNK_S; ++c)
      s += part[(o * NCHUNK_S + c) * 33 * 64 + idx];
    stats[o * 33 * 64 + idx] = s;
  }
}

// ---------------- finish M-step: mu, mi4 {m0,i0,m1,i1}, base ----------------
__global__ __launch_bounds__(64) void k_finish(const float* __restrict__ stats,
                                               const float* __restrict__ beta_u,
                                               const float* __restrict__ beta_a,
                                               float* __restrict__ mu,
                                               float* __restrict__ mi4,
                                               float* __restrict__ basew) {
  int o = blockIdx.x, b = threadIdx.x;
  const float* st = stats + o * 33 * 64;
  float s0 = st[b];
  float rs = s0 + EMEPS;
  float inv_rs = 1.0f / rs;
  float ldet = 0.f;
  float mloc[16], iloc[16];
#pragma unroll
  for (int d = 0; d < 16; ++d) {
    float s1 = st[(1 + d) * 64 + b];
    float s2 = st[(17 + d) * 64 + b];
    float m = s1 * inv_rs;
    float var = (s2 - 2.0f * m * s1 + m * m * s0) * inv_rs;
    float sg = fmaxf(var, 0.0f) + EMEPS;
    mloc[d] = m;
    iloc[d] = 1.0f / sg;
    mu[(o * 16 + d) * 64 + b] = m;
    ldet += logf(sg);
  }
#pragma unroll
  for (int q = 0; q < 8; ++q) {
    float4 v = {mloc[2*q], iloc[2*q], mloc[2*q+1], iloc[2*q+1]};
    *(float4*)&mi4[((o * 8 + q) * 64 + b) * 4] = v;
  }
  float cost = (16.0f * beta_u[o] + 0.5f * ldet) * rs;
  float x = beta_a[o] - cost;
  float a = 1.0f / (1.0f + expf(-x));
  basew[o * 64 + b] = logf(a + EMEPS) - 0.5f * ldet;
}

// ---------------- fused E-step: logp + softmax ----------------
template <bool FINAL>
__global__ __launch_bounds__(256) void k_estep(const unsigned* __restrict__ V,
                                               const float* __restrict__ mi4,
                                               const float* __restrict__ basew,
                                               unsigned short* __restrict__ Rh,
                                               float* __restrict__ qout) {
  int t = threadIdx.x, b = t & 63, ng = t >> 6;
  int n = blockIdx.x * 4 + ng;
  float l[25];
  float mx = -1e30f;
#pragma unroll
  for (int o = 0; o < 25; ++o) {
    const uint4* vp = (const uint4*)(V + (((size_t)n * 25 + o) * 64 + b) * 8);
    uint4 u0 = vp[0], u1 = vp[1];
    unsigned uu[8] = {u0.x, u0.y, u0.z, u0.w, u1.x, u1.y, u1.z, u1.w};
    float acc = 0.f;
#pragma unroll
    for (int qq = 0; qq < 8; ++qq) {
      float4 mi = *(const float4*)&mi4[((o * 8 + qq) * 64 + b) * 4];
      float d0 = f16lo(uu[qq]) - mi.x;
      float d1 = f16hi(uu[qq]) - mi.z;
      acc += d0 * d0 * mi.y + d1 * d1 * mi.w;
    }
    l[o] = basew[o * 64 + b] - 0.5f * acc;
    mx = fmaxf(mx, l[o]);
  }
  float s = 0.f;
#pragma unroll
  for (int o = 0; o < 25; ++o) { l[o] = expf(l[o] - mx); s += l[o]; }
  float inv = 1.0f / s;
  if (FINAL) {
    float* qp = qout + ((size_t)b * NPRI + n) * 25;
#pragma unroll
    for (int o = 0; o < 25; ++o) qp[o] = l[o] * inv;
  } else {
#pragma unroll
    for (int o = 0; o < 25; ++o)
      Rh[((size_t)n * 25 + o) * 64 + b] = f16bits(l[o] * inv);
  }
}

// ---------------- epilogue ----------------
__global__ __launch_bounds__(64) void k_out(const float* __restrict__ mu,
                                            const float* __restrict__ g2,
                                            const float* __restrict__ bb2,
                                            const float* __restrict__ w3,
                                            const float* __restrict__ b3,
                                            float* __restrict__ out) {
  int o = blockIdx.x, b = threadIdx.x;
  float m[16];
  float s = 0.f;
#pragma unroll
  for (int d = 0; d < 16; ++d) { m[d] = mu[(o * 16 + d) * 64 + b]; s += m[d]; }
  float mean = s * (1.0f / 16.0f);
  float var = 0.f;
#pragma unroll
  for (int d = 0; d < 16; ++d) { float dd = m[d] - mean; var += dd * dd; }
  var *= (1.0f / 16.0f);
  float inv = 1.0f / sqrtf(var + LNEPS);
  float logit = 0.f, nrm = 0.f;
#pragma unroll
  for (int d = 0; d < 16; ++d) {
    float nh = (m[d] - mean) * inv * g2[d] + bb2[d];
    logit += nh * w3[d];
    nrm += m[d] * m[d];
  }
  out[b * 25 + o] = logit + b3[0];
  out[1600 + b * 25 + o] = sqrtf(nrm);
  float* pp = out + 3200 + (b * 25 + o) * 16;
#pragma unroll
  for (int d = 0; d < 16; ++d) pp[d] = m[d];
}

extern "C" void kernel_launch(void* const* d_in, const int* in_sizes, int n_in,
                              void* d_out, int out_size, void* d_ws, size_t ws_size,
                              hipStream_t stream) {
  const float* z      = (const float*)d_in[0];
  const float* w1     = (const float*)d_in[1];
  const float* b1     = (const float*)d_in[2];
  const float* ln1g   = (const float*)d_in[3];
  const float* ln1b   = (const float*)d_in[4];
  const float* w2     = (const float*)d_in[5];
  const float* b2     = (const float*)d_in[6];
  const float* wcaps  = (const float*)d_in[7];
  const float* beta_u = (const float*)d_in[8];
  const float* beta_a = (const float*)d_in[9];
  const float* ln2g   = (const float*)d_in[10];
  const float* ln2b   = (const float*)d_in[11];
  const float* w3     = (const float*)d_in[12];
  const float* b3     = (const float*)d_in[13];

  if (ws_size < (size_t)WS_FLOATS * 4) {
    fprintf(stderr, "kernel_launch: ws too small: %zu < %zu bytes\n",
            ws_size, (size_t)WS_FLOATS * 4);
  }

  float* ws    = (float*)d_ws;
  float* out   = (float*)d_out;
  float* poseT = ws + OFF_POSE;
  float* zn    = ws + OFF_ZN;
  float* actt  = ws + OFF_ACTT;
  float* g2p   = ws + OFF_G2P;
  unsigned* V  = (unsigned*)(ws + OFF_V);
  unsigned short* Rh = (unsigned short*)(ws + OFF_R);
  float* part  = ws + OFF_PART;
  float* st    = ws + OFF_STAT;
  float* muw   = ws + OFF_MU;
  float* mi4   = ws + OFF_MI4;
  float* bse   = ws + OFF_BASE;

  k_ln<<<64, 256, 0, stream>>>(z, ln1g, ln1b, zn);
  k_gemm1<<<512, 256, 0, stream>>>(z, w1, b1, poseT);
  k_gemm2p<<<dim3(32, KS2), 256, 0, stream>>>(zn, w2, g2p);
  k_gemm2r<<<128, 256, 0, stream>>>(g2p, b2, actt);
  k_votes<<<2048, 256, 0, stream>>>(poseT, wcaps, V);

  // iteration 1 (uniform R)
  k_stats<true><<<dim3(NCHUNK_S, 25), 256, 0, stream>>>(V, actt, Rh, part);
  k_reduce<<<25, 256, 0, stream>>>(part, st);
  k_finish<<<25, 64, 0, stream>>>(st, beta_u, beta_a, muw, mi4, bse);

  // iterations 2,3
  for (int it = 0; it < 2; ++it) {
    k_estep<false><<<512, 256, 0, stream>>>(V, mi4, bse, Rh, nullptr);
    k_stats<false><<<dim3(NCHUNK_S, 25), 256, 0, stream>>>(V, actt, Rh, part);
    k_reduce<<<25, 256, 0, stream>>>(part, st);
    k_finish<<<25, 64, 0, stream>>>(st, beta_u, beta_a, muw, mi4, bse);
  }

  // final E-step -> q, then outputs
  k_estep<true><<<512, 256, 0, stream>>>(V, mi4, bse, nullptr, out + 28800);
  k_out<<<25, 64, 0, stream>>>(muw, ln2g, ln2b, w3, b3, out);
}